// Round 13
// baseline (625.517 us; speedup 1.0000x reference)
//
#include <hip/hip_runtime.h>

typedef unsigned long long u64;
typedef unsigned int u32;
typedef unsigned short u16;

#define N_ROWS 16384
#define DIM    512
#define K_CODES 8192

#define CHUNKS 32
#define CHUNK_CODES 256
#define BMS 256
#define KC 32
#define VTILES 32            // 2 sub-chunks x 16 K-tiles

typedef short bf16x8 __attribute__((ext_vector_type(8)));
typedef float f32x4  __attribute__((ext_vector_type(4)));

#define LBUF 24576           // u16 per 48KB buffer: Ah[256][32]@0 Am@8192 Bh[128][32]@16384 Bm@20480

__device__ __forceinline__ void t2_insert(u64* a, u64 k) {
    u64 lo = a[0], hi = a[1];
    bool lt0 = k < lo;
    u64 n1k = (k < hi) ? k : hi;
    a[0] = lt0 ? k : lo;
    a[1] = lt0 ? lo : n1k;
}

// ---------------- Kernel P: precompute bf16 bit-truncation splits (verified r5) ----
__global__ void vq_split_kernel(const float* __restrict__ x, const float* __restrict__ cb,
                                u16* __restrict__ xhi, u16* __restrict__ xmid,
                                u16* __restrict__ cbhi, u16* __restrict__ cbmid) {
    size_t t = (size_t)blockIdx.x * blockDim.x + threadIdx.x;
    const size_t nx = (size_t)N_ROWS * DIM / 4;
    const size_t nc = (size_t)K_CODES * DIM / 4;
    const float4* src;
    u16 *hi, *mid;
    size_t off;
    if (t < nx)            { src = (const float4*)x;  hi = xhi;  mid = xmid;  off = t; }
    else if (t < nx + nc)  { src = (const float4*)cb; hi = cbhi; mid = cbmid; off = t - nx; }
    else return;
    float4 v = src[off];
    u32 b0 = __float_as_uint(v.x), b1 = __float_as_uint(v.y),
        b2 = __float_as_uint(v.z), b3 = __float_as_uint(v.w);
    u16 h0 = (u16)(b0 >> 16), h1 = (u16)(b1 >> 16), h2 = (u16)(b2 >> 16), h3 = (u16)(b3 >> 16);
    u16 m0 = (u16)(__float_as_uint(v.x - __uint_as_float(b0 & 0xFFFF0000u)) >> 16);
    u16 m1 = (u16)(__float_as_uint(v.y - __uint_as_float(b1 & 0xFFFF0000u)) >> 16);
    u16 m2 = (u16)(__float_as_uint(v.z - __uint_as_float(b2 & 0xFFFF0000u)) >> 16);
    u16 m3 = (u16)(__float_as_uint(v.w - __uint_as_float(b3 & 0xFFFF0000u)) >> 16);
    ((ushort4*)hi)[off]  = make_ushort4(h0, h1, h2, h3);
    ((ushort4*)mid)[off] = make_ushort4(m0, m1, m2, m3);
}

// ---------------- Kernel N: numpy-pairwise fp32 row norms (verified r3) ----------------
__device__ __forceinline__ float np_block128_sq(const float* __restrict__ q) {
    float r[8];
    #pragma unroll
    for (int j = 0; j < 8; ++j) r[j] = __fmul_rn(q[j], q[j]);
    for (int i = 8; i < 128; i += 8) {
        #pragma unroll
        for (int j = 0; j < 8; ++j) r[j] = __fadd_rn(r[j], __fmul_rn(q[i + j], q[i + j]));
    }
    return __fadd_rn(__fadd_rn(__fadd_rn(r[0], r[1]), __fadd_rn(r[2], r[3])),
                     __fadd_rn(__fadd_rn(r[4], r[5]), __fadd_rn(r[6], r[7])));
}

__global__ void vq_np_norm_kernel(const float* __restrict__ x, const float* __restrict__ cb,
                                  float* __restrict__ Arow, float* __restrict__ Bcode) {
    int t = blockIdx.x * blockDim.x + threadIdx.x;
    const float* p;
    float* o;
    if (t < N_ROWS) {
        p = x + (size_t)t * DIM;  o = Arow + t;
    } else if (t < N_ROWS + K_CODES) {
        int j = t - N_ROWS;
        p = cb + (size_t)j * DIM; o = Bcode + j;
    } else return;
    float b0 = np_block128_sq(p);
    float b1 = np_block128_sq(p + 128);
    float b2 = np_block128_sq(p + 256);
    float b3 = np_block128_sq(p + 384);
    *o = __fadd_rn(__fadd_rn(b0, b1), __fadd_rn(b2, b3));
}

// ---------------- Kernel S: reads-ahead pipelined MFMA screen -----------------------
// 256 rows x (2 x 128 codes) per block; 8 waves 4M x 2N, wave tile 64x64.
// 3 x 48KB LDS, depth-2: stage(vt+2) issued AFTER the entry barrier of vt;
// entry s_waitcnt vmcnt(6) drains exactly tile vt's 6 loads. ONE barrier/tile.
// Within a tile: {read Ah,Bh,Bm} -> hh MFMAs -> {read Am} -> hm -> mh (pure-reg).
// Per-acc-element MFMA order kt asc x {hh,hm,mh} == r5-r12 -> bit-identical scores.
__launch_bounds__(512, 2)
__global__ void vq_screen_kernel(const u16* __restrict__ xhi, const u16* __restrict__ xmid,
                                 const u16* __restrict__ cbhi, const u16* __restrict__ cbmid,
                                 const float* __restrict__ Arow,
                                 const float* __restrict__ Bcode,
                                 u64* __restrict__ top2out) {
    __shared__ __align__(16) u16 lds[3 * LBUF];   // 144KB

    const int t = threadIdx.x;
    const int lane = t & 63;
    const int w = t >> 6;        // 0..7
    const int wm = w >> 1;       // 0..3 -> rows [64*wm, +64)
    const int wn = w & 1;        // 0..1 -> cols [64*wn, +64) within the 128-chunk
    const int r15 = lane & 15;
    const int g = lane >> 4;     // 0..3
    const int cswz = (r15 >> 1) & 3;

    const int rowBase   = blockIdx.x * BMS;
    const int chunkBase = blockIdx.y * CHUNK_CODES;

    // per-lane pre-swizzled source offset (verified r9: conflict-free with read side)
    const size_t laneOff = (size_t)(lane >> 2) * DIM
                         + (size_t)(((lane & 3) ^ ((lane >> 3) & 3)) * 8);

    // 6 staging sources per wave; dest = seg q * 512 with q = {w, w+8, w+16, w+24, w+32, w+40}
    const u16* s0 = xhi   + (size_t)(rowBase + w * 16) * DIM + laneOff;        // Ah
    const u16* s1 = xhi   + (size_t)(rowBase + (w + 8) * 16) * DIM + laneOff;  // Ah
    const u16* s2 = xmid  + (size_t)(rowBase + w * 16) * DIM + laneOff;        // Am
    const u16* s3 = xmid  + (size_t)(rowBase + (w + 8) * 16) * DIM + laneOff;  // Am
    const u16* s4 = cbhi  + (size_t)(chunkBase + w * 16) * DIM + laneOff;      // Bh
    const u16* s5 = cbmid + (size_t)(chunkBase + w * 16) * DIM + laneOff;      // Bm
    const int d0 = w * 512, d1 = (w + 8) * 512, d2 = 8192 + w * 512,
              d3 = 8192 + (w + 8) * 512, d4 = 16384 + w * 512, d5 = 20480 + w * 512;

    auto stage = [&](int vt) {
        const size_t ko = (size_t)((vt & 15) * KC);
        const size_t co = (size_t)((vt >> 4) * 128) * DIM + ko;
        u16* B = &lds[(vt % 3) * LBUF];
        __builtin_amdgcn_global_load_lds((const __attribute__((address_space(1))) u32*)(s0 + ko), (__attribute__((address_space(3))) u32*)(B + d0), 16, 0, 0);
        __builtin_amdgcn_global_load_lds((const __attribute__((address_space(1))) u32*)(s1 + ko), (__attribute__((address_space(3))) u32*)(B + d1), 16, 0, 0);
        __builtin_amdgcn_global_load_lds((const __attribute__((address_space(1))) u32*)(s2 + ko), (__attribute__((address_space(3))) u32*)(B + d2), 16, 0, 0);
        __builtin_amdgcn_global_load_lds((const __attribute__((address_space(1))) u32*)(s3 + ko), (__attribute__((address_space(3))) u32*)(B + d3), 16, 0, 0);
        __builtin_amdgcn_global_load_lds((const __attribute__((address_space(1))) u32*)(s4 + co), (__attribute__((address_space(3))) u32*)(B + d4), 16, 0, 0);
        __builtin_amdgcn_global_load_lds((const __attribute__((address_space(1))) u32*)(s5 + co), (__attribute__((address_space(3))) u32*)(B + d5), 16, 0, 0);
    };

    f32x4 acc[4][4] = {};
    u64 t2[4][4][2];
    #pragma unroll
    for (int mi = 0; mi < 4; ++mi)
        #pragma unroll
        for (int reg = 0; reg < 4; ++reg) { t2[mi][reg][0] = ~0ull; t2[mi][reg][1] = ~0ull; }

    stage(0);
    stage(1);

    for (int vt = 0; vt < VTILES; ++vt) {
        if (vt + 1 < VTILES) asm volatile("s_waitcnt vmcnt(6)" ::: "memory");
        else                 asm volatile("s_waitcnt vmcnt(0)" ::: "memory");
        asm volatile("s_barrier" ::: "memory");
        if (vt + 2 < VTILES) stage(vt + 2);

        const u16* L = &lds[(vt % 3) * LBUF];
        bf16x8 Ah[4], Bh[4], Bm[4], Am[4];
        #pragma unroll
        for (int mi = 0; mi < 4; ++mi)
            Ah[mi] = *(const bf16x8*)&L[(wm * 64 + mi * 16 + r15) * 32 + (g ^ cswz) * 8];
        #pragma unroll
        for (int ni = 0; ni < 4; ++ni) {
            int b = (wn * 64 + ni * 16 + r15) * 32 + (g ^ cswz) * 8;
            Bh[ni] = *(const bf16x8*)&L[16384 + b];
            Bm[ni] = *(const bf16x8*)&L[20480 + b];
        }
        // ---- hh ----
        __builtin_amdgcn_s_setprio(1);
        #pragma unroll
        for (int ni = 0; ni < 4; ++ni)
            #pragma unroll
            for (int mi = 0; mi < 4; ++mi)
                acc[mi][ni] = __builtin_amdgcn_mfma_f32_16x16x32_bf16(Ah[mi], Bh[ni], acc[mi][ni], 0, 0, 0);
        __builtin_amdgcn_s_setprio(0);
        // ---- Am reads land under hm ----
        #pragma unroll
        for (int mi = 0; mi < 4; ++mi)
            Am[mi] = *(const bf16x8*)&L[8192 + (wm * 64 + mi * 16 + r15) * 32 + (g ^ cswz) * 8];
        __builtin_amdgcn_s_setprio(1);
        #pragma unroll
        for (int ni = 0; ni < 4; ++ni)
            #pragma unroll
            for (int mi = 0; mi < 4; ++mi)
                acc[mi][ni] = __builtin_amdgcn_mfma_f32_16x16x32_bf16(Ah[mi], Bm[ni], acc[mi][ni], 0, 0, 0);
        // ---- mh: pure-register ----
        #pragma unroll
        for (int ni = 0; ni < 4; ++ni)
            #pragma unroll
            for (int mi = 0; mi < 4; ++mi)
                acc[mi][ni] = __builtin_amdgcn_mfma_f32_16x16x32_bf16(Am[mi], Bh[ni], acc[mi][ni], 0, 0, 0);
        __builtin_amdgcn_s_setprio(0);

        if ((vt & 15) == 15) {
            // fold this 128-code sub-chunk into persistent per-lane top-2
            const int ct = vt >> 4;
            float bjv[4];
            #pragma unroll
            for (int ni = 0; ni < 4; ++ni)
                bjv[ni] = Bcode[chunkBase + ct * 128 + wn * 64 + ni * 16 + r15];
            #pragma unroll
            for (int mi = 0; mi < 4; ++mi) {
                float AiV[4];
                #pragma unroll
                for (int reg = 0; reg < 4; ++reg)
                    AiV[reg] = Arow[rowBase + wm * 64 + mi * 16 + g * 4 + reg];
                #pragma unroll
                for (int ni = 0; ni < 4; ++ni) {
                    int col = chunkBase + ct * 128 + wn * 64 + ni * 16 + r15;
                    #pragma unroll
                    for (int reg = 0; reg < 4; ++reg) {
                        float d = __fsub_rn(__fadd_rn(AiV[reg], bjv[ni]), 2.0f * acc[mi][ni][reg]);
                        u64 key = ((u64)__float_as_uint(d) << 13) | (u64)(u32)col;
                        t2_insert(t2[mi][reg], key);
                    }
                    acc[mi][ni] = (f32x4){0.0f, 0.0f, 0.0f, 0.0f};
                }
            }
        }
    }

    // ---- cross-lane merge over the 16 column-lanes ----
    #pragma unroll
    for (int m = 1; m <= 8; m <<= 1) {
        #pragma unroll
        for (int mi = 0; mi < 4; ++mi)
            #pragma unroll
            for (int reg = 0; reg < 4; ++reg) {
                u64 i0 = __shfl_xor(t2[mi][reg][0], m);
                u64 i1 = __shfl_xor(t2[mi][reg][1], m);
                t2_insert(t2[mi][reg], i0);
                t2_insert(t2[mi][reg], i1);
            }
    }

    // ---- merge across the 2 wn waves via LDS, write chunk top-2 ----
    __syncthreads();
    u64* t2buf = (u64*)&lds[0];   // [256 rows][2 wn][2 slots] = 8KB
    if (r15 == 0) {
        #pragma unroll
        for (int mi = 0; mi < 4; ++mi)
            #pragma unroll
            for (int reg = 0; reg < 4; ++reg) {
                int row = wm * 64 + mi * 16 + g * 4 + reg;
                t2buf[(row * 2 + wn) * 2 + 0] = t2[mi][reg][0];
                t2buf[(row * 2 + wn) * 2 + 1] = t2[mi][reg][1];
            }
    }
    __syncthreads();
    if (t < BMS) {
        u64 best[2];
        best[0] = t2buf[(t * 2 + 0) * 2 + 0];
        best[1] = t2buf[(t * 2 + 0) * 2 + 1];
        t2_insert(best, t2buf[(t * 2 + 1) * 2 + 0]);
        t2_insert(best, t2buf[(t * 2 + 1) * 2 + 1]);
        top2out[((size_t)blockIdx.y * N_ROWS + rowBase + t) * 2 + 0] = best[0];
        top2out[((size_t)blockIdx.y * N_ROWS + rowBase + t) * 2 + 1] = best[1];
    }
}

// ---------------- Kernel R: chunk-top2 -> exact np re-decision (verified r8-r12) ----
__global__ void vq_refine_kernel(const float* __restrict__ x, const float* __restrict__ cb,
                                 const float* __restrict__ Arow, const float* __restrict__ Bcode,
                                 const u64* __restrict__ top2, int* __restrict__ idxOut,
                                 float* __restrict__ out4) {
    int gw = (blockIdx.x * blockDim.x + threadIdx.x) >> 6;
    int lane = threadIdx.x & 63;
    if (gw >= N_ROWS) return;

    u64 key = top2[((size_t)(lane >> 1) * N_ROWS + gw) * 2 + (lane & 1)];

    u64 m1 = key;
    #pragma unroll
    for (int m = 1; m < 16; m <<= 1) { u64 o = __shfl_xor(m1, m); m1 = o < m1 ? o : m1; }
    u64 k2 = (key == m1) ? ~0ull : key;
    u64 m2 = k2;
    #pragma unroll
    for (int m = 1; m < 16; m <<= 1) { u64 o = __shfl_xor(m2, m); m2 = o < m2 ? o : m2; }

    float Ai = Arow[gw];
    const float* xr = x + (size_t)gw * DIM;
    u64 best = ~0ull;
    #pragma unroll
    for (int j = 0; j < 8; ++j) {
        u64 ck = __shfl((j & 1) ? m2 : m1, (j >> 1) * 16);
        int c = (int)(ck & 8191u);
        const float* er = cb + (size_t)c * DIM;
        double d = 0.0;
        #pragma unroll
        for (int e = 0; e < 8; ++e)
            d = fma((double)xr[e * 64 + lane], (double)er[e * 64 + lane], d);
        #pragma unroll
        for (int m = 1; m < 64; m <<= 1) d += __shfl_xor(d, m);
        float m32 = (float)d;
        float dist = __fsub_rn(__fadd_rn(Ai, Bcode[c]), 2.0f * m32);
        u64 ek = ((u64)__float_as_uint(dist) << 13) | (u64)(u32)c;
        best = ek < best ? ek : best;
    }
    if (lane == 0) {
        int c = (int)(best & 8191u);
        idxOut[gw] = c;
        out4[gw] = (float)c;
    }
}

// ---------------- Kernel C: gather + outputs + per-row loss partial ----------------
__global__ void vq_gather_kernel(const float* __restrict__ x,
                                 const float* __restrict__ cb,
                                 const int* __restrict__ idxArr,
                                 float* __restrict__ out0,
                                 float* __restrict__ out3,
                                 float* __restrict__ rowPart) {
    int gw = (blockIdx.x * blockDim.x + threadIdx.x) >> 6;
    int lane = threadIdx.x & 63;
    if (gw >= N_ROWS) return;
    int idx = idxArr[gw];
    const float2* xp = (const float2*)(x  + (size_t)gw * DIM);
    const float2* qp = (const float2*)(cb + (size_t)idx * DIM);
    float2* o0 = (float2*)(out0 + (size_t)gw * DIM);
    float2* o3 = (float2*)(out3 + (size_t)gw * DIM);
    float part = 0.0f;
    #pragma unroll
    for (int r = 0; r < 4; ++r) {
        int e = r * 64 + lane;
        float2 xv = xp[e];
        float2 qv = qp[e];
        float dx = qv.x - xv.x, dy = qv.y - xv.y;
        part += dx * dx + dy * dy;
        float2 o; o.x = xv.x + dx; o.y = xv.y + dy;
        o0[e] = o;
        o3[e] = qv;
    }
    #pragma unroll
    for (int m = 32; m; m >>= 1) part += __shfl_xor(part, m);
    if (lane == 0) rowPart[gw] = part;
}

// ---------------- Kernel D: deterministic loss reduce ----------------
__global__ void vq_loss_kernel(const float* __restrict__ rowPart,
                               float* __restrict__ out1, float* __restrict__ out2) {
    __shared__ float red[256];
    int t = threadIdx.x;
    float s = 0.0f;
    for (int r = t; r < N_ROWS; r += 256) s += rowPart[r];
    red[t] = s;
    __syncthreads();
    #pragma unroll
    for (int m = 128; m; m >>= 1) {
        if (t < m) red[t] += red[t + m];
        __syncthreads();
    }
    if (t == 0) {
        float loss = red[0] / (float)(N_ROWS * DIM);
        out1[0] = loss;
        out2[0] = loss;
    }
}

extern "C" void kernel_launch(void* const* d_in, const int* in_sizes, int n_in,
                              void* d_out, int out_size, void* d_ws, size_t ws_size,
                              hipStream_t stream) {
    const float* x  = (const float*)d_in[0];   // [16384, 512]
    const float* cb = (const float*)d_in[1];   // [8192, 512]
    float* out  = (float*)d_out;
    float* out0 = out;                         // quantized_out [8388608]
    float* out1 = out + 8388608;               // q_latent_loss [1]
    float* out2 = out + 8388609;               // e_latent_loss [1]
    float* out3 = out + 8388610;               // quantized [8388608]
    float* out4 = out + 16777218;              // idx as float [16384]

    // d_out doubles as scratch until refine/gather consume & overwrite (stream-ordered):
    // splits in [0, 12582916); chunk-top2 in the out3 tail [12582916, 14680068).
    u16* xhi   = (u16*)out0;                       // [0, 4194304) floats
    u16* xmid  = (u16*)(out + 4194304);            // [4194304, 8388608)
    u16* cbhi  = (u16*)(out + 8388612);            // [8388612, 10485764)  16B-aligned
    u16* cbmid = (u16*)(out + 10485764);           // [10485764, 12582916)
    u64* wsTop2 = (u64*)(out + 12582916);          // 32*16384*2 u64 = 8MB

    char* ws = (char*)d_ws;
    float* wsA    = (float*)ws;                    // 16384 f
    float* wsB    = (float*)(ws + 65536);          // 8192 f
    int*   wsIdx  = (int*)(ws + 98304);            // 16384 int
    float* wsPart = (float*)(ws + 163840);         // 16384 f

    hipLaunchKernelGGL(vq_split_kernel,   dim3(12288), dim3(256), 0, stream,
                       x, cb, xhi, xmid, cbhi, cbmid);
    hipLaunchKernelGGL(vq_np_norm_kernel, dim3(96), dim3(256), 0, stream, x, cb, wsA, wsB);
    hipLaunchKernelGGL(vq_screen_kernel,  dim3(N_ROWS / BMS, CHUNKS), dim3(512), 0, stream,
                       xhi, xmid, cbhi, cbmid, wsA, wsB, wsTop2);
    hipLaunchKernelGGL(vq_refine_kernel,  dim3(4096), dim3(256), 0, stream,
                       x, cb, wsA, wsB, wsTop2, wsIdx, out4);
    hipLaunchKernelGGL(vq_gather_kernel,  dim3(4096), dim3(256), 0, stream,
                       x, cb, wsIdx, out0, out3, wsPart);
    hipLaunchKernelGGL(vq_loss_kernel,    dim3(1),   dim3(256), 0, stream,
                       wsPart, out1, out2);
}

// Round 14
// 434.628 us; speedup vs baseline: 1.4392x; 1.4392x over previous
//
#include <hip/hip_runtime.h>

typedef unsigned long long u64;
typedef unsigned int u32;
typedef unsigned short u16;

#define N_ROWS 16384
#define DIM    512
#define K_CODES 8192

#define CHUNKS 64
#define CHUNK_CODES 128
#define BMR 128
#define KC 32
#define KTILES (DIM / KC)    // 16

typedef short bf16x8 __attribute__((ext_vector_type(8)));
typedef float f32x4  __attribute__((ext_vector_type(4)));

// sorted ascending 3-slot insert (bubble-through, branchless; r4-verified pattern)
__device__ __forceinline__ void t3_insert(u64* a, u64 k) {
    u64 x = k;
    bool l0 = x < a[0]; u64 n0 = l0 ? x : a[0]; x = l0 ? a[0] : x;
    bool l1 = x < a[1]; u64 n1 = l1 ? x : a[1]; x = l1 ? a[1] : x;
    bool l2 = x < a[2]; u64 n2 = l2 ? x : a[2];
    a[0] = n0; a[1] = n1; a[2] = n2;
}

// ---------------- Kernel P: precompute bf16 HI-plane split only ----------------
__global__ void vq_split_kernel(const float* __restrict__ x, const float* __restrict__ cb,
                                u16* __restrict__ xhi, u16* __restrict__ cbhi) {
    size_t t = (size_t)blockIdx.x * blockDim.x + threadIdx.x;
    const size_t nx = (size_t)N_ROWS * DIM / 4;
    const size_t nc = (size_t)K_CODES * DIM / 4;
    const float4* src;
    u16* hi;
    size_t off;
    if (t < nx)            { src = (const float4*)x;  hi = xhi;  off = t; }
    else if (t < nx + nc)  { src = (const float4*)cb; hi = cbhi; off = t - nx; }
    else return;
    float4 v = src[off];
    u16 h0 = (u16)(__float_as_uint(v.x) >> 16);
    u16 h1 = (u16)(__float_as_uint(v.y) >> 16);
    u16 h2 = (u16)(__float_as_uint(v.z) >> 16);
    u16 h3 = (u16)(__float_as_uint(v.w) >> 16);
    ((ushort4*)hi)[off] = make_ushort4(h0, h1, h2, h3);
}

// ---------------- Kernel N: numpy-pairwise fp32 row norms (verified r3) ----------------
__device__ __forceinline__ float np_block128_sq(const float* __restrict__ q) {
    float r[8];
    #pragma unroll
    for (int j = 0; j < 8; ++j) r[j] = __fmul_rn(q[j], q[j]);
    for (int i = 8; i < 128; i += 8) {
        #pragma unroll
        for (int j = 0; j < 8; ++j) r[j] = __fadd_rn(r[j], __fmul_rn(q[i + j], q[i + j]));
    }
    return __fadd_rn(__fadd_rn(__fadd_rn(r[0], r[1]), __fadd_rn(r[2], r[3])),
                     __fadd_rn(__fadd_rn(r[4], r[5]), __fadd_rn(r[6], r[7])));
}

__global__ void vq_np_norm_kernel(const float* __restrict__ x, const float* __restrict__ cb,
                                  float* __restrict__ Arow, float* __restrict__ Bcode) {
    int t = blockIdx.x * blockDim.x + threadIdx.x;
    const float* p;
    float* o;
    if (t < N_ROWS) {
        p = x + (size_t)t * DIM;  o = Arow + t;
    } else if (t < N_ROWS + K_CODES) {
        int j = t - N_ROWS;
        p = cb + (size_t)j * DIM; o = Bcode + j;
    } else return;
    float b0 = np_block128_sq(p);
    float b1 = np_block128_sq(p + 128);
    float b2 = np_block128_sq(p + 256);
    float b3 = np_block128_sq(p + 384);
    *o = __fadd_rn(__fadd_rn(b0, b1), __fadd_rn(b2, b3));
}

// ---------------- Kernel S: hh-only MFMA screen, 128x128 blocks, 4 blocks/CU ----------
// 256 threads, 4 waves 2M x 2N, wave tile 64x64 (16 MFMA/tile/wave, 8 ds_read_b128).
// LDS 2 x 16KB (Ah[128][32] | Bh[128][32]); depth-1 prefetch, counted vmcnt(4).
// Chunk-XOR swizzle both sides (r9-verified). Screen noise sigma~1e-5 << kept-set
// margin: top-3/chunk + global top-8 exact refine (see analysis).
__launch_bounds__(256, 4)
__global__ void vq_screen_kernel(const u16* __restrict__ xhi, const u16* __restrict__ cbhi,
                                 const float* __restrict__ Arow,
                                 const float* __restrict__ Bcode,
                                 u64* __restrict__ top3out) {
    __shared__ __align__(16) u16 lds[2][8192];   // 2 x 16KB

    const int t = threadIdx.x;
    const int lane = t & 63;
    const int w = t >> 6;        // 0..3
    const int wm = w >> 1;       // 0..1 -> rows [64*wm, +64)
    const int wn = w & 1;        // 0..1 -> cols [64*wn, +64)
    const int r15 = lane & 15;
    const int g = lane >> 4;     // 0..3
    const int cswz = (r15 >> 1) & 3;

    const int rowBase   = blockIdx.x * BMR;
    const int chunkBase = blockIdx.y * CHUNK_CODES;

    // per-lane pre-swizzled source offset (LDS dest linear; read applies same XOR)
    const size_t laneOff = (size_t)(lane >> 2) * DIM
                         + (size_t)(((lane & 3) ^ ((lane >> 3) & 3)) * 8);

    // 4 staging segments per wave: q = j*4 + w over [Ah groups 0-7 | Bh groups 8-15]
    const u16* srcs[4];
    int dsts[4];
    #pragma unroll
    for (int j = 0; j < 4; ++j) {
        int q = j * 4 + w;
        const u16* gp = (q < 8) ? (xhi + (size_t)(rowBase + q * 16) * DIM)
                                : (cbhi + (size_t)(chunkBase + (q - 8) * 16) * DIM);
        srcs[j] = gp + laneOff;
        dsts[j] = q * 512;
    }

    auto stage = [&](int kt, int b) {
        #pragma unroll
        for (int j = 0; j < 4; ++j) {
            __builtin_amdgcn_global_load_lds(
                (const __attribute__((address_space(1))) u32*)(srcs[j] + kt * KC),
                (__attribute__((address_space(3))) u32*)(&lds[b][dsts[j]]),
                16, 0, 0);
        }
    };

    f32x4 acc[4][4] = {};

    stage(0, 0);

    #pragma unroll
    for (int kt = 0; kt < KTILES; ++kt) {
        if (kt + 1 < KTILES) {
            stage(kt + 1, (kt + 1) & 1);
            asm volatile("s_waitcnt vmcnt(4)" ::: "memory");
        } else {
            asm volatile("s_waitcnt vmcnt(0)" ::: "memory");
        }
        asm volatile("s_barrier" ::: "memory");

        const u16* L = &lds[kt & 1][0];
        bf16x8 Ah[4], Bh[4];
        #pragma unroll
        for (int mi = 0; mi < 4; ++mi)
            Ah[mi] = *(const bf16x8*)&L[(wm * 64 + mi * 16 + r15) * 32 + (g ^ cswz) * 8];
        #pragma unroll
        for (int ni = 0; ni < 4; ++ni)
            Bh[ni] = *(const bf16x8*)&L[4096 + (wn * 64 + ni * 16 + r15) * 32 + (g ^ cswz) * 8];
        __builtin_amdgcn_s_setprio(1);
        #pragma unroll
        for (int ni = 0; ni < 4; ++ni)
            #pragma unroll
            for (int mi = 0; mi < 4; ++mi)
                acc[mi][ni] = __builtin_amdgcn_mfma_f32_16x16x32_bf16(Ah[mi], Bh[ni], acc[mi][ni], 0, 0, 0);
        __builtin_amdgcn_s_setprio(0);
        asm volatile("s_barrier" ::: "memory");
    }

    // ---- fold once: hh acc -> screened dist -> per-row top-3 of this 128-chunk ----
    float bjv[4];
    #pragma unroll
    for (int ni = 0; ni < 4; ++ni)
        bjv[ni] = Bcode[chunkBase + wn * 64 + ni * 16 + r15];

    __syncthreads();
    u64* t3buf = (u64*)&lds[0][0];   // [128 rows][2 wn][3 slots] = 6KB

    #pragma unroll
    for (int mi = 0; mi < 4; ++mi) {
        float AiV[4];
        #pragma unroll
        for (int reg = 0; reg < 4; ++reg)
            AiV[reg] = Arow[rowBase + wm * 64 + mi * 16 + g * 4 + reg];
        u64 t3r[4][3];
        #pragma unroll
        for (int reg = 0; reg < 4; ++reg) { t3r[reg][0] = ~0ull; t3r[reg][1] = ~0ull; t3r[reg][2] = ~0ull; }
        #pragma unroll
        for (int ni = 0; ni < 4; ++ni) {
            int col = chunkBase + wn * 64 + ni * 16 + r15;
            #pragma unroll
            for (int reg = 0; reg < 4; ++reg) {
                float d = __fsub_rn(__fadd_rn(AiV[reg], bjv[ni]), 2.0f * acc[mi][ni][reg]);
                u64 key = ((u64)__float_as_uint(d) << 13) | (u64)(u32)col;
                t3_insert(t3r[reg], key);
            }
        }
        #pragma unroll
        for (int m = 1; m <= 8; m <<= 1) {
            #pragma unroll
            for (int reg = 0; reg < 4; ++reg) {
                u64 i0 = __shfl_xor(t3r[reg][0], m);
                u64 i1 = __shfl_xor(t3r[reg][1], m);
                u64 i2 = __shfl_xor(t3r[reg][2], m);
                t3_insert(t3r[reg], i0);
                t3_insert(t3r[reg], i1);
                t3_insert(t3r[reg], i2);
            }
        }
        if (r15 == 0) {
            #pragma unroll
            for (int reg = 0; reg < 4; ++reg) {
                int row = wm * 64 + mi * 16 + g * 4 + reg;
                t3buf[(row * 2 + wn) * 3 + 0] = t3r[reg][0];
                t3buf[(row * 2 + wn) * 3 + 1] = t3r[reg][1];
                t3buf[(row * 2 + wn) * 3 + 2] = t3r[reg][2];
            }
        }
    }
    __syncthreads();
    if (t < BMR) {
        u64 best[3];
        best[0] = t3buf[(t * 2 + 0) * 3 + 0];
        best[1] = t3buf[(t * 2 + 0) * 3 + 1];
        best[2] = t3buf[(t * 2 + 0) * 3 + 2];
        t3_insert(best, t3buf[(t * 2 + 1) * 3 + 0]);
        t3_insert(best, t3buf[(t * 2 + 1) * 3 + 1]);
        t3_insert(best, t3buf[(t * 2 + 1) * 3 + 2]);
        size_t o = ((size_t)blockIdx.y * N_ROWS + rowBase + t) * 3;
        top3out[o + 0] = best[0];
        top3out[o + 1] = best[1];
        top3out[o + 2] = best[2];
    }
}

// ---------------- Kernel R: global top-8 of 64x3 keys -> exact np re-decision --------
__global__ void vq_refine_kernel(const float* __restrict__ x, const float* __restrict__ cb,
                                 const float* __restrict__ Arow, const float* __restrict__ Bcode,
                                 const u64* __restrict__ top3, int* __restrict__ idxOut,
                                 float* __restrict__ out4) {
    int gw = (blockIdx.x * blockDim.x + threadIdx.x) >> 6;
    int lane = threadIdx.x & 63;
    if (gw >= N_ROWS) return;

    // lane = chunk (0..63): its sorted top-3 keys
    const u64* tp = top3 + ((size_t)lane * N_ROWS + gw) * 3;
    u64 a0 = tp[0], a1 = tp[1], a2 = tp[2];

    // pop global min 8 times (keys unique: col bits differ)
    u64 cand[8];
    #pragma unroll
    for (int j = 0; j < 8; ++j) {
        u64 m = a0;
        #pragma unroll
        for (int s = 1; s < 64; s <<= 1) { u64 o = __shfl_xor(m, s); m = o < m ? o : m; }
        cand[j] = m;
        if (a0 == m) { a0 = a1; a1 = a2; a2 = ~0ull; }
    }

    float Ai = Arow[gw];
    const float* xr = x + (size_t)gw * DIM;
    u64 best = ~0ull;
    #pragma unroll
    for (int j = 0; j < 8; ++j) {
        int c = (int)(cand[j] & 8191u);
        const float* er = cb + (size_t)c * DIM;
        double d = 0.0;
        #pragma unroll
        for (int e = 0; e < 8; ++e)
            d = fma((double)xr[e * 64 + lane], (double)er[e * 64 + lane], d);
        #pragma unroll
        for (int m = 1; m < 64; m <<= 1) d += __shfl_xor(d, m);
        float m32 = (float)d;
        float dist = __fsub_rn(__fadd_rn(Ai, Bcode[c]), 2.0f * m32);
        u64 ek = ((u64)__float_as_uint(dist) << 13) | (u64)(u32)c;
        best = ek < best ? ek : best;
    }
    if (lane == 0) {
        int c = (int)(best & 8191u);
        idxOut[gw] = c;
        out4[gw] = (float)c;
    }
}

// ---------------- Kernel C: gather + outputs + per-row loss partial ----------------
__global__ void vq_gather_kernel(const float* __restrict__ x,
                                 const float* __restrict__ cb,
                                 const int* __restrict__ idxArr,
                                 float* __restrict__ out0,
                                 float* __restrict__ out3,
                                 float* __restrict__ rowPart) {
    int gw = (blockIdx.x * blockDim.x + threadIdx.x) >> 6;
    int lane = threadIdx.x & 63;
    if (gw >= N_ROWS) return;
    int idx = idxArr[gw];
    const float2* xp = (const float2*)(x  + (size_t)gw * DIM);
    const float2* qp = (const float2*)(cb + (size_t)idx * DIM);
    float2* o0 = (float2*)(out0 + (size_t)gw * DIM);
    float2* o3 = (float2*)(out3 + (size_t)gw * DIM);
    float part = 0.0f;
    #pragma unroll
    for (int r = 0; r < 4; ++r) {
        int e = r * 64 + lane;
        float2 xv = xp[e];
        float2 qv = qp[e];
        float dx = qv.x - xv.x, dy = qv.y - xv.y;
        part += dx * dx + dy * dy;
        float2 o; o.x = xv.x + dx; o.y = xv.y + dy;
        o0[e] = o;
        o3[e] = qv;
    }
    #pragma unroll
    for (int m = 32; m; m >>= 1) part += __shfl_xor(part, m);
    if (lane == 0) rowPart[gw] = part;
}

// ---------------- Kernel D: deterministic loss reduce ----------------
__global__ void vq_loss_kernel(const float* __restrict__ rowPart,
                               float* __restrict__ out1, float* __restrict__ out2) {
    __shared__ float red[256];
    int t = threadIdx.x;
    float s = 0.0f;
    for (int r = t; r < N_ROWS; r += 256) s += rowPart[r];
    red[t] = s;
    __syncthreads();
    #pragma unroll
    for (int m = 128; m; m >>= 1) {
        if (t < m) red[t] += red[t + m];
        __syncthreads();
    }
    if (t == 0) {
        float loss = red[0] / (float)(N_ROWS * DIM);
        out1[0] = loss;
        out2[0] = loss;
    }
}

extern "C" void kernel_launch(void* const* d_in, const int* in_sizes, int n_in,
                              void* d_out, int out_size, void* d_ws, size_t ws_size,
                              hipStream_t stream) {
    const float* x  = (const float*)d_in[0];   // [16384, 512]
    const float* cb = (const float*)d_in[1];   // [8192, 512]
    float* out  = (float*)d_out;
    float* out0 = out;                         // quantized_out [8388608]
    float* out1 = out + 8388608;               // q_latent_loss [1]
    float* out2 = out + 8388609;               // e_latent_loss [1]
    float* out3 = out + 8388610;               // quantized [8388608]
    float* out4 = out + 16777218;              // idx as float [16384]

    // d_out scratch (stream-ordered; consumed before gather overwrites):
    // xhi 16MB + cbhi 8MB in out0 region; top3 (64*16384*3 u64 = 24MB) in out3 region.
    u16* xhi    = (u16*)out0;                  // [0, 4194304) floats
    u16* cbhi   = (u16*)(out + 4194304);       // [4194304, 6291456)
    u64* wsTop3 = (u64*)(out + 8388612);       // [8388612, 14680068)  8B-aligned

    char* ws = (char*)d_ws;
    float* wsA    = (float*)ws;                // 16384 f
    float* wsB    = (float*)(ws + 65536);      // 8192 f
    int*   wsIdx  = (int*)(ws + 98304);        // 16384 int
    float* wsPart = (float*)(ws + 163840);     // 16384 f

    hipLaunchKernelGGL(vq_split_kernel,   dim3(12288), dim3(256), 0, stream,
                       x, cb, xhi, cbhi);
    hipLaunchKernelGGL(vq_np_norm_kernel, dim3(96), dim3(256), 0, stream, x, cb, wsA, wsB);
    hipLaunchKernelGGL(vq_screen_kernel,  dim3(N_ROWS / BMR, CHUNKS), dim3(256), 0, stream,
                       xhi, cbhi, wsA, wsB, wsTop3);
    hipLaunchKernelGGL(vq_refine_kernel,  dim3(4096), dim3(256), 0, stream,
                       x, cb, wsA, wsB, wsTop3, wsIdx, out4);
    hipLaunchKernelGGL(vq_gather_kernel,  dim3(4096), dim3(256), 0, stream,
                       x, cb, wsIdx, out0, out3, wsPart);
    hipLaunchKernelGGL(vq_loss_kernel,    dim3(1),   dim3(256), 0, stream,
                       wsPart, out1, out2);
}